// Round 14
// baseline (9737.556 us; speedup 1.0000x reference)
//
#include <hip/hip_runtime.h>
#include <stdint.h>
#include <stdio.h>

// Problem constants
#define TL 1024          // T
#define BB 64            // B
#define HH 512           // H
#define II 1024          // input size (== 2H for layer 2)
#define NL 2             // layers
#define BT_ (BB*TL)      // 65536
#define G3_ 1536         // 3H
#define N2_ 3072         // 2*3H (both dirs stacked)

typedef _Float16 h8 __attribute__((ext_vector_type(8)));
typedef _Float16 h4 __attribute__((ext_vector_type(4)));
typedef _Float16 h2 __attribute__((ext_vector_type(2)));
typedef float    f4 __attribute__((ext_vector_type(4)));
typedef unsigned int u4 __attribute__((ext_vector_type(4)));
typedef unsigned int u2v __attribute__((ext_vector_type(2)));

// ---------------- fp32 -> fp16 convert ----------------
__global__ void cvt_f2h(const float* __restrict__ src, _Float16* __restrict__ dst, size_t n4) {
  size_t i = (size_t)blockIdx.x*blockDim.x + threadIdx.x;
  size_t stride = (size_t)gridDim.x*blockDim.x;
  for (; i < n4; i += stride) {
    f4 v = ((const f4*)src)[i];
    h4 o;
    o[0] = (_Float16)v[0]; o[1] = (_Float16)v[1];
    o[2] = (_Float16)v[2]; o[3] = (_Float16)v[3];
    ((h4*)dst)[i] = o;
  }
}

// ---------------- gi GEMM (unchanged, proven) ----------------
#define LDA 40
__launch_bounds__(256)
__global__ void gemm_gi(const _Float16* __restrict__ A, const _Float16* __restrict__ Bw,
                        const float* __restrict__ bias, _Float16* __restrict__ gi)
{
  const int bn = blockIdx.x, bm = blockIdx.y;
  const int tid = threadIdx.x;
  const int wave = tid >> 6, lane = tid & 63;
  const int wm = wave >> 1, wn = wave & 1;
  const int lo = lane & 15, hi = lane >> 4;
  __shared__ _Float16 As[128*LDA];
  __shared__ _Float16 Bs[128*LDA];
  f4 acc[4][4] = {};
  const int r0 = tid >> 2, c0 = (tid & 3)*8;
  const _Float16* Ag = A + (size_t)(bm*128)*II;
  const _Float16* Bg = Bw + (size_t)(bn*128)*II;
  u4 a0 = *(const u4*)(Ag + (size_t)r0*II + c0);
  u4 a1 = *(const u4*)(Ag + (size_t)(64+r0)*II + c0);
  u4 b0 = *(const u4*)(Bg + (size_t)r0*II + c0);
  u4 b1 = *(const u4*)(Bg + (size_t)(64+r0)*II + c0);
  for (int kt = 0; kt < 32; ++kt) {
    __syncthreads();
    *(u4*)&As[r0*LDA + c0] = a0;
    *(u4*)&As[(64+r0)*LDA + c0] = a1;
    *(u4*)&Bs[r0*LDA + c0] = b0;
    *(u4*)&Bs[(64+r0)*LDA + c0] = b1;
    if (kt+1 < 32) {
      const int off = (kt+1)*32 + c0;
      a0 = *(const u4*)(Ag + (size_t)r0*II + off);
      a1 = *(const u4*)(Ag + (size_t)(64+r0)*II + off);
      b0 = *(const u4*)(Bg + (size_t)r0*II + off);
      b1 = *(const u4*)(Bg + (size_t)(64+r0)*II + off);
    }
    __syncthreads();
    h8 af[4], bf[4];
    #pragma unroll
    for (int i = 0; i < 4; ++i)
      af[i] = *(const h8*)&As[(wm*64 + i*16 + lo)*LDA + hi*8];
    #pragma unroll
    for (int j = 0; j < 4; ++j)
      bf[j] = *(const h8*)&Bs[(wn*64 + j*16 + lo)*LDA + hi*8];
    #pragma unroll
    for (int i = 0; i < 4; ++i)
      #pragma unroll
      for (int j = 0; j < 4; ++j)
        acc[i][j] = __builtin_amdgcn_mfma_f32_16x16x32_f16(af[i], bf[j], acc[i][j], 0, 0, 0);
  }
  const int nbase = bn*128 + wn*64;
  const int mbase = bm*128 + wm*64;
  #pragma unroll
  for (int j = 0; j < 4; ++j) {
    int n = nbase + j*16 + lo;
    int dir = (n >= G3_) ? 1 : 0;
    int row = n - dir*G3_;
    float bs = bias[n];
    #pragma unroll
    for (int i = 0; i < 4; ++i) {
      int m0 = mbase + i*16 + hi*4;
      #pragma unroll
      for (int v = 0; v < 4; ++v)
        gi[((size_t)dir*BT_ + (size_t)(m0+v))*G3_ + row] = (_Float16)(acc[i][j][v] + bs);
    }
  }
}

// ---------------- persistent GRU layer (R8 tagged-mailbox + clean ew queues) ----------------
// 128 blocks x 384 threads. gg=bid&7: d=gg&1, g=gg>>1 (batch-chunk of 16).
// member=bid>>3 owns j-slice [member*32,+32), 3 gates of W_hh in LDS.
// Mailbox protocol (R6/R8-proven): 8B entries {h2|tag<<32}, relaxed agent 8B
// atomics; read step s: parity s&1, tag>=s+1; publish end of s: parity (s+1)&1,
// tag s+2, fire-forget atomic store; 2-step back-pressure induction; memset.
// R8's quad structure kept VERBATIM: all 16 E loads in flight, 4 quads of
// {per-lane verify + 32B thread-local retry, stage, lgkm+raw-barrier, 4 MFMA}.
// NEW (R14, vmcnt-in-order lesson): ew waves 0-3 carry ONLY mailbox traffic.
//  - gi: waves 4-5 register-hold load (issued a full step early) -> gil LDS
//    ring, post-bar2 window; ew reads gi from LDS (lgkm, not vmcnt).
//  - out: ew hands values to olds[par][256] LDS; waves 4-5 store to HBM one
//    step later (their own queue; all 256 slots covered unconditionally).
//  - E(s+1) issued at END of elementwise (lead time ~= publish window).
#define LDW 520
__launch_bounds__(384, 1)
__global__ void gru_layer(const _Float16* __restrict__ gi,     // [dir][b*T+t][1536]
                          const _Float16* __restrict__ whh,    // layer: [dir][1536][512]
                          const float* __restrict__ bhh,       // layer: [dir][1536]
                          const float* __restrict__ h0,        // [4][64][512]
                          unsigned long long* __restrict__ tagh, // layer: [d][par][64][256] u64
                          _Float16* __restrict__ out_mid,      // layer0: [b][t][1024] fp16
                          float* __restrict__ out_fin,         // layer1: [b][t][1024] fp32
                          float* __restrict__ hn_out,          // [4][64][512] fp32
                          int layer)
{
  const int bid = blockIdx.x;
  const int gg = bid & 7, d = gg & 1, g = gg >> 1;
  const int member = bid >> 3;
  const int j0 = member * 32, b0 = g * 16;
  const int tid = threadIdx.x;
  const int wave = tid >> 6, lane = tid & 63, lo = lane & 15, hi = lane >> 4;
  const int gate = wave >> 1, jh = wave & 1;     // 6 waves: 3 gates x 2 j-halves

  __shared__ _Float16 wlds[3][32][LDW];
  __shared__ _Float16 hlds[16][LDW];
  __shared__ float    ghlds[3][32][17];
  __shared__ _Float16 gil[2][16][3][32];         // gi ring: [par][batch][gate][32 halves]
  __shared__ u2v      olds[2][256];              // out handoff: [par][eb*16+ejp]

  // --- load resident W_hh slice ---
  const _Float16* wsrc = whh + (size_t)d*G3_*HH;
  #pragma unroll
  for (int it = 0; it < 16; ++it) {
    int idx = it*384 + tid;
    int row = idx >> 6;
    int c8 = (idx & 63) * 8;
    int gt = row >> 5, jj = row & 31;
    u4 v = *(const u4*)(wsrc + (size_t)(gt*HH + j0 + jj)*HH + c8);
    *(u4*)&wlds[gt][jj][c8] = v;
  }

  const int ejp = tid & 15;              // j-pair within slice
  const int eb  = tid >> 4;              // 0..15 batch within chunk (ew threads)
  const bool ew = (tid < 256);
  const bool ldr = (wave >= 4);          // waves 4-5: gi loader + out storer
  const int Lid = tid - 256;             // loader lane id 0..127
  const int ejA = j0 + 2*ejp;

  unsigned long long* Tb = tagh + (size_t)d*2*BB*256;   // this direction's 2 parities

  float hj[2];
  float bhr[2], bhz[2], bhn[2];
  unsigned long long E[16];
  u4 vc0 = {}, vc1 = {};                 // loader register-hold (gi for step s+1)

  if (ew) {
    #pragma unroll
    for (int u = 0; u < 2; ++u) {
      bhr[u] = bhh[(size_t)d*G3_ + 0*HH + ejA + u];
      bhz[u] = bhh[(size_t)d*G3_ + 1*HH + ejA + u];
      bhn[u] = bhh[(size_t)d*G3_ + 2*HH + ejA + u];
      hj[u]  = h0[((size_t)(2*layer + d)*BB + b0 + eb)*HH + ejA + u];
    }
    h2 p; p[0] = (_Float16)hj[0]; p[1] = (_Float16)hj[1];
    unsigned long long ent = (unsigned long long)__builtin_bit_cast(unsigned, p) | (1ull << 32);
    unsigned long long* ptr = Tb + (size_t)0*BB*256 + (size_t)(b0 + eb)*256 + (member*16 + ejp);
    __hip_atomic_store(ptr, ent, __ATOMIC_RELAXED, __HIP_MEMORY_SCOPE_AGENT);
    // issue E(0) (parity 0)
    #pragma unroll
    for (int q = 0; q < 4; ++q)
      #pragma unroll
      for (int k = 0; k < 4; ++k) {
        int i = tid*2 + (k >> 1);
        E[q*4+k] = __hip_atomic_load(
            Tb + (size_t)(b0 + (i >> 5))*256 + q*64 + (i & 31)*2 + (k & 1),
            __ATOMIC_RELAXED, __HIP_MEMORY_SCOPE_AGENT);
      }
  }
  if (ldr) {
    // prologue: gi(0) -> gil[0] (one-time vmcnt exposure); issue gi(1) -> regs
    const int t0 = d ? (TL-1) : 0;
    const int t1 = d ? (TL-2) : 1;
    {
      int seg = Lid >> 2, q = Lid & 3, gt = seg >> 4, b = seg & 15;
      u4 v = *(const u4*)(gi + (size_t)d*BT_*G3_ + ((size_t)(b0+b)*TL + t0)*(size_t)G3_ + gt*HH + j0 + q*8);
      *(u4*)&gil[0][b][gt][q*8] = v;
      vc0 = *(const u4*)(gi + (size_t)d*BT_*G3_ + ((size_t)(b0+b)*TL + t1)*(size_t)G3_ + gt*HH + j0 + q*8);
    }
    if (Lid < 64) {
      int i1 = Lid + 128;
      int seg = i1 >> 2, q = i1 & 3, gt = seg >> 4, b = seg & 15;
      u4 v = *(const u4*)(gi + (size_t)d*BT_*G3_ + ((size_t)(b0+b)*TL + t0)*(size_t)G3_ + gt*HH + j0 + q*8);
      *(u4*)&gil[0][b][gt][q*8] = v;
      vc1 = *(const u4*)(gi + (size_t)d*BT_*G3_ + ((size_t)(b0+b)*TL + t1)*(size_t)G3_ + gt*HH + j0 + q*8);
    }
  }
  __syncthreads();   // wlds + gil[0] ready; E(0) in flight or drained

  for (int s = 0; s < TL; ++s) {
    const int t = d ? (TL-1 - s) : s;
    const int rpar = s & 1, wpar = rpar ^ 1;
    const unsigned tgt = (unsigned)(s + 1);
    const unsigned long long* Trd = Tb + (size_t)rpar*BB*256;

    // ---- 4 quads: per-lane verify + stage + barrier + MFMA (R8 verbatim) ----
    f4 acc = {0.f, 0.f, 0.f, 0.f};
    #pragma unroll
    for (int q = 0; q < 4; ++q) {
      if (ew) {
        for (;;) {
          unsigned ok = 1u;
          #pragma unroll
          for (int k = 0; k < 4; ++k)
            ok &= (unsigned)((E[q*4+k] >> 32) >= tgt);
          if (ok) break;
          #pragma unroll
          for (int k = 0; k < 4; ++k) {
            int i = tid*2 + (k >> 1);
            E[q*4+k] = __hip_atomic_load(
                Trd + (size_t)(b0 + (i >> 5))*256 + q*64 + (i & 31)*2 + (k & 1),
                __ATOMIC_RELAXED, __HIP_MEMORY_SCOPE_AGENT);
          }
        }
        #pragma unroll
        for (int k = 0; k < 2; ++k) {
          int i = tid*2 + k;
          int b = i >> 5, p = i & 31;
          u2v dv; dv[0] = (unsigned)E[q*4 + k*2]; dv[1] = (unsigned)E[q*4 + k*2 + 1];
          *(u2v*)&hlds[b][q*128 + p*4] = dv;
        }
      }
      asm volatile("s_waitcnt lgkmcnt(0)" ::: "memory");
      __builtin_amdgcn_s_barrier();                     // raw: vmcnt NOT drained
      __builtin_amdgcn_sched_barrier(0);
      #pragma unroll
      for (int kk = q*4; kk < q*4 + 4; ++kk) {
        h8 af = *(const h8*)&hlds[lo][kk*32 + hi*8];
        h8 bf = *(const h8*)&wlds[gate][jh*16 + lo][kk*32 + hi*8];
        acc = __builtin_amdgcn_mfma_f32_16x16x32_f16(af, bf, acc, 0, 0, 0);
      }
    }
    #pragma unroll
    for (int v = 0; v < 4; ++v)
      ghlds[gate][jh*16 + lo][hi*4 + v] = acc[v];   // [gate][j][b]
    __syncthreads();   // bar2: ghlds ready; frees hlds for next step
    // ---- post-bar2 window: ew elementwise+publish  ||  loader duties ----
    if (ew) {
      unsigned giR = *(const unsigned*)&gil[rpar][eb][0][2*ejp];
      unsigned giZ = *(const unsigned*)&gil[rpar][eb][1][2*ejp];
      unsigned giN = *(const unsigned*)&gil[rpar][eb][2][2*ejp];
      h2 pR = __builtin_bit_cast(h2, giR);
      h2 pZ = __builtin_bit_cast(h2, giZ);
      h2 pN = __builtin_bit_cast(h2, giN);
      h2 hnew; float hv[2];
      #pragma unroll
      for (int u = 0; u < 2; ++u) {
        float ir = (float)pR[u], iz = (float)pZ[u], inn = (float)pN[u];
        float hr = ghlds[0][2*ejp+u][eb] + bhr[u];
        float hz = ghlds[1][2*ejp+u][eb] + bhz[u];
        float hn = ghlds[2][2*ejp+u][eb] + bhn[u];
        float rr = 1.f/(1.f + __expf(-(ir + hr)));
        float zz = 1.f/(1.f + __expf(-(iz + hz)));
        float xx = inn + rr*hn;
        float nn = 1.f - 2.f/(__expf(2.f*xx) + 1.f);   // tanh, overflow-safe
        float h  = (1.f - zz)*nn + zz*hj[u];
        hj[u] = h; hnew[u] = (_Float16)h; hv[u] = h;
      }
      unsigned hu = __builtin_bit_cast(unsigned, hnew);
      u2v ov;
      if (out_mid) { ov[0] = hu; ov[1] = hu; }
      else { ov[0] = __builtin_bit_cast(unsigned, hv[0]); ov[1] = __builtin_bit_cast(unsigned, hv[1]); }
      olds[rpar][tid] = ov;                            // handoff (read by loaders at s+1)
      unsigned long long ent = (unsigned long long)hu | ((unsigned long long)(s + 2) << 32);
      unsigned long long* ptr = Tb + (size_t)wpar*BB*256 + (size_t)(b0 + eb)*256 + (member*16 + ejp);
      __hip_atomic_store(ptr, ent, __ATOMIC_RELAXED, __HIP_MEMORY_SCOPE_AGENT);
      // issue E(s+1) (parity wpar) with the inter-step window as lead time
      const unsigned long long* Trn = Tb + (size_t)wpar*BB*256;
      #pragma unroll
      for (int q = 0; q < 4; ++q)
        #pragma unroll
        for (int k = 0; k < 4; ++k) {
          int i = tid*2 + (k >> 1);
          E[q*4+k] = __hip_atomic_load(
              Trn + (size_t)(b0 + (i >> 5))*256 + q*64 + (i & 31)*2 + (k & 1),
              __ATOMIC_RELAXED, __HIP_MEMORY_SCOPE_AGENT);
        }
    } else {
      // write gil for step s+1 from regs loaded a full step ago (no vmcnt wait)
      {
        int seg = Lid >> 2, q = Lid & 3, gt = seg >> 4, b = seg & 15;
        *(u4*)&gil[wpar][b][gt][q*8] = vc0;
      }
      if (Lid < 64) {
        int i1 = Lid + 128;
        int seg = i1 >> 2, q = i1 & 3, gt = seg >> 4, b = seg & 15;
        *(u4*)&gil[wpar][b][gt][q*8] = vc1;
      }
      // issue gi(s+2) -> regs (clamped; tail value never read)
      {
        int sn = (s + 2 < TL) ? s + 2 : TL - 1;
        int tn = d ? (TL-1 - sn) : sn;
        int seg = Lid >> 2, q = Lid & 3, gt = seg >> 4, b = seg & 15;
        vc0 = *(const u4*)(gi + (size_t)d*BT_*G3_ + ((size_t)(b0+b)*TL + tn)*(size_t)G3_ + gt*HH + j0 + q*8);
        if (Lid < 64) {
          int i1 = Lid + 128;
          int seg1 = i1 >> 2, q1 = i1 & 3, gt1 = seg1 >> 4, b1 = seg1 & 15;
          vc1 = *(const u4*)(gi + (size_t)d*BT_*G3_ + ((size_t)(b0+b1)*TL + tn)*(size_t)G3_ + gt1*HH + j0 + q1*8);
        }
      }
      // out store for step s-1 (olds[wpar], written by ew at s-1; both slots unconditional)
      if (s > 0) {
        int tp = d ? (TL-1 - (s-1)) : (s-1);
        {
          int b = Lid >> 4, jp = Lid & 15;
          u2v o0 = olds[wpar][Lid];
          if (out_mid) *(unsigned*)(out_mid + ((size_t)(b0+b)*TL + tp)*(size_t)(2*HH) + d*HH + j0 + 2*jp) = o0[0];
          else         *(u2v*)(out_fin + ((size_t)(b0+b)*TL + tp)*(size_t)(2*HH) + d*HH + j0 + 2*jp) = o0;
        }
        {
          int i1 = Lid + 128;
          int b = i1 >> 4, jp = i1 & 15;
          u2v o1 = olds[wpar][i1];
          if (out_mid) *(unsigned*)(out_mid + ((size_t)(b0+b)*TL + tp)*(size_t)(2*HH) + d*HH + j0 + 2*jp) = o1[0];
          else         *(u2v*)(out_fin + ((size_t)(b0+b)*TL + tp)*(size_t)(2*HH) + d*HH + j0 + 2*jp) = o1;
        }
      }
    }
    // no end barrier: next step's quad0 lgkm+barrier provides separation
  }
  // final flush: out of step TL-1 (olds[(TL-1)&1]) + hn
  asm volatile("s_waitcnt lgkmcnt(0)" ::: "memory");
  __builtin_amdgcn_s_barrier();
  __builtin_amdgcn_sched_barrier(0);
  if (ldr) {
    const int fpar = (TL-1) & 1;
    int tp = d ? 0 : (TL-1);
    {
      int b = Lid >> 4, jp = Lid & 15;
      u2v o0 = olds[fpar][Lid];
      if (out_mid) *(unsigned*)(out_mid + ((size_t)(b0+b)*TL + tp)*(size_t)(2*HH) + d*HH + j0 + 2*jp) = o0[0];
      else         *(u2v*)(out_fin + ((size_t)(b0+b)*TL + tp)*(size_t)(2*HH) + d*HH + j0 + 2*jp) = o0;
    }
    {
      int i1 = Lid + 128;
      int b = i1 >> 4, jp = i1 & 15;
      u2v o1 = olds[fpar][i1];
      if (out_mid) *(unsigned*)(out_mid + ((size_t)(b0+b)*TL + tp)*(size_t)(2*HH) + d*HH + j0 + 2*jp) = o1[0];
      else         *(u2v*)(out_fin + ((size_t)(b0+b)*TL + tp)*(size_t)(2*HH) + d*HH + j0 + 2*jp) = o1;
    }
  }
  if (ew) {
    #pragma unroll
    for (int u = 0; u < 2; ++u)
      hn_out[((size_t)(2*layer + d)*BB + b0 + eb)*HH + ejA + u] = hj[u];
  }
}

// ---------------- host launcher ----------------
extern "C" void kernel_launch(void* const* d_in, const int* in_sizes, int n_in,
                              void* d_out, int out_size, void* d_ws, size_t ws_size,
                              hipStream_t stream) {
  (void)in_sizes; (void)n_in; (void)out_size;
  const float* x   = (const float*)d_in[0];
  const float* h0  = (const float*)d_in[1];
  const float* wih = (const float*)d_in[2];
  const float* whh = (const float*)d_in[3];
  const float* bih = (const float*)d_in[4];
  const float* bhh = (const float*)d_in[5];
  float* out = (float*)d_out;

  char* ws = (char*)d_ws;
  size_t off = 0;
  auto alloc = [&](size_t bytes) {
    char* p = ws + off;
    off += (bytes + 255) & ~(size_t)255;
    return p;
  };
  _Float16* x16   = (_Float16*)alloc((size_t)BT_*II*2);          // 128 MB
  _Float16* mid16 = (_Float16*)alloc((size_t)BT_*II*2);          // 128 MB
  _Float16* gi16  = (_Float16*)alloc((size_t)2*BT_*G3_*2);       // 384 MB
  _Float16* wih16 = (_Float16*)alloc((size_t)NL*N2_*II*2);       // 12 MB
  _Float16* whh16 = (_Float16*)alloc((size_t)NL*N2_*HH*2);       // 6 MB
  unsigned long long* tagh = (unsigned long long*)alloc((size_t)NL*2*2*BB*256*8); // 1 MB
  if (off > ws_size) {
    fprintf(stderr, "kernel_launch: workspace too small: need %zu have %zu\n", off, ws_size);
    return;
  }

  hipMemsetAsync(tagh, 0, (size_t)NL*2*2*BB*256*8, stream);      // clear stale tags (per replay)
  cvt_f2h<<<2048, 256, 0, stream>>>(x,   x16,   (size_t)BT_*II/4);
  cvt_f2h<<<512,  256, 0, stream>>>(wih, wih16, (size_t)NL*N2_*II/4);
  cvt_f2h<<<512,  256, 0, stream>>>(whh, whh16, (size_t)NL*N2_*HH/4);

  float* hn = out + (size_t)BT_*II;   // h_n region: (4,64,512) after (B,T,2H)

  // layer 0
  gemm_gi<<<dim3(24, 512), 256, 0, stream>>>(x16, wih16, bih, gi16);
  gru_layer<<<128, 384, 0, stream>>>(gi16, whh16, bhh, h0, tagh,
                                     mid16, nullptr, hn, 0);
  // layer 1
  gemm_gi<<<dim3(24, 512), 256, 0, stream>>>(mid16, wih16 + (size_t)N2_*II, bih + N2_, gi16);
  gru_layer<<<128, 384, 0, stream>>>(gi16, whh16 + (size_t)N2_*HH, bhh + N2_, h0,
                                     tagh + (size_t)2*2*BB*256, nullptr, out, hn, 1);
}

// Round 15
// 8188.491 us; speedup vs baseline: 1.1892x; 1.1892x over previous
//
#include <hip/hip_runtime.h>
#include <stdint.h>
#include <stdio.h>

// Problem constants
#define TL 1024          // T
#define BB 64            // B
#define HH 512           // H
#define II 1024          // input size (== 2H for layer 2)
#define NL 2             // layers
#define BT_ (BB*TL)      // 65536
#define G3_ 1536         // 3H
#define N2_ 3072         // 2*3H (both dirs stacked)

typedef _Float16 h8 __attribute__((ext_vector_type(8)));
typedef _Float16 h4 __attribute__((ext_vector_type(4)));
typedef _Float16 h2 __attribute__((ext_vector_type(2)));
typedef float    f4 __attribute__((ext_vector_type(4)));
typedef unsigned int u4 __attribute__((ext_vector_type(4)));
typedef unsigned int u2v __attribute__((ext_vector_type(2)));

// ---------------- fp32 -> fp16 convert ----------------
__global__ void cvt_f2h(const float* __restrict__ src, _Float16* __restrict__ dst, size_t n4) {
  size_t i = (size_t)blockIdx.x*blockDim.x + threadIdx.x;
  size_t stride = (size_t)gridDim.x*blockDim.x;
  for (; i < n4; i += stride) {
    f4 v = ((const f4*)src)[i];
    h4 o;
    o[0] = (_Float16)v[0]; o[1] = (_Float16)v[1];
    o[2] = (_Float16)v[2]; o[3] = (_Float16)v[3];
    ((h4*)dst)[i] = o;
  }
}

// ---------------- gi GEMM (unchanged, proven) ----------------
#define LDA 40
__launch_bounds__(256)
__global__ void gemm_gi(const _Float16* __restrict__ A, const _Float16* __restrict__ Bw,
                        const float* __restrict__ bias, _Float16* __restrict__ gi)
{
  const int bn = blockIdx.x, bm = blockIdx.y;
  const int tid = threadIdx.x;
  const int wave = tid >> 6, lane = tid & 63;
  const int wm = wave >> 1, wn = wave & 1;
  const int lo = lane & 15, hi = lane >> 4;
  __shared__ _Float16 As[128*LDA];
  __shared__ _Float16 Bs[128*LDA];
  f4 acc[4][4] = {};
  const int r0 = tid >> 2, c0 = (tid & 3)*8;
  const _Float16* Ag = A + (size_t)(bm*128)*II;
  const _Float16* Bg = Bw + (size_t)(bn*128)*II;
  u4 a0 = *(const u4*)(Ag + (size_t)r0*II + c0);
  u4 a1 = *(const u4*)(Ag + (size_t)(64+r0)*II + c0);
  u4 b0 = *(const u4*)(Bg + (size_t)r0*II + c0);
  u4 b1 = *(const u4*)(Bg + (size_t)(64+r0)*II + c0);
  for (int kt = 0; kt < 32; ++kt) {
    __syncthreads();
    *(u4*)&As[r0*LDA + c0] = a0;
    *(u4*)&As[(64+r0)*LDA + c0] = a1;
    *(u4*)&Bs[r0*LDA + c0] = b0;
    *(u4*)&Bs[(64+r0)*LDA + c0] = b1;
    if (kt+1 < 32) {
      const int off = (kt+1)*32 + c0;
      a0 = *(const u4*)(Ag + (size_t)r0*II + off);
      a1 = *(const u4*)(Ag + (size_t)(64+r0)*II + off);
      b0 = *(const u4*)(Bg + (size_t)r0*II + off);
      b1 = *(const u4*)(Bg + (size_t)(64+r0)*II + off);
    }
    __syncthreads();
    h8 af[4], bf[4];
    #pragma unroll
    for (int i = 0; i < 4; ++i)
      af[i] = *(const h8*)&As[(wm*64 + i*16 + lo)*LDA + hi*8];
    #pragma unroll
    for (int j = 0; j < 4; ++j)
      bf[j] = *(const h8*)&Bs[(wn*64 + j*16 + lo)*LDA + hi*8];
    #pragma unroll
    for (int i = 0; i < 4; ++i)
      #pragma unroll
      for (int j = 0; j < 4; ++j)
        acc[i][j] = __builtin_amdgcn_mfma_f32_16x16x32_f16(af[i], bf[j], acc[i][j], 0, 0, 0);
  }
  const int nbase = bn*128 + wn*64;
  const int mbase = bm*128 + wm*64;
  #pragma unroll
  for (int j = 0; j < 4; ++j) {
    int n = nbase + j*16 + lo;
    int dir = (n >= G3_) ? 1 : 0;
    int row = n - dir*G3_;
    float bs = bias[n];
    #pragma unroll
    for (int i = 0; i < 4; ++i) {
      int m0 = mbase + i*16 + hi*4;
      #pragma unroll
      for (int v = 0; v < 4; ++v)
        gi[((size_t)dir*BT_ + (size_t)(m0+v))*G3_ + row] = (_Float16)(acc[i][j][v] + bs);
    }
  }
}

// ---------------- persistent GRU layer kernel (R8 tagged-mailbox, E-before-gi issue) ----------------
// 128 blocks x 384 threads. gg=bid&7: d=gg&1, g=gg>>1 (batch-chunk of 16).
// member=bid>>3 owns j-slice [member*32,+32), all 3 gates resident in LDS.
// Mailbox (R6/R8-proven): 8B entries {h2|tag<<32}, relaxed agent-scope 8B
// atomics; read step s: parity s&1, tag>=s+1; publish end of s: parity
// (s+1)&1, tag s+2, fire-and-forget; 2-step back-pressure induction; memset.
// Quad structure (R8 verbatim): all 16 E loads up-front, 4 quads of
// {per-lane verify + 32B thread-local retry, stage, lgkm+raw-barrier, 4 MFMA}.
// R15 change (vmcnt in-order retirement): issue E loads BEFORE the gi HBM
// loads (sched_barrier-pinned). Quad-0's verify-wait then drains only
// publish/out (aged) + E (LLC RT) - NOT the just-issued ~900cy HBM gi loads,
// which retire under the verify/MFMA shadow and are waited on only at
// elementwise, ~2us after issue. (R8 had gi first: every step's first verify
// paid full HBM latency before E became readable.)
#define LDW 520
__launch_bounds__(384, 1)
__global__ void gru_layer(const _Float16* __restrict__ gi,     // [dir][b*T+t][1536]
                          const _Float16* __restrict__ whh,    // layer: [dir][1536][512]
                          const float* __restrict__ bhh,       // layer: [dir][1536]
                          const float* __restrict__ h0,        // [4][64][512]
                          unsigned long long* __restrict__ tagh, // layer: [d][par][64][256] u64
                          _Float16* __restrict__ out_mid,      // layer0: [b][t][1024] fp16
                          float* __restrict__ out_fin,         // layer1: [b][t][1024] fp32
                          float* __restrict__ hn_out,          // [4][64][512] fp32
                          int layer)
{
  const int bid = blockIdx.x;
  const int gg = bid & 7, d = gg & 1, g = gg >> 1;
  const int member = bid >> 3;
  const int j0 = member * 32, b0 = g * 16;
  const int tid = threadIdx.x;
  const int wave = tid >> 6, lane = tid & 63, lo = lane & 15, hi = lane >> 4;
  const int gate = wave >> 1, jh = wave & 1;     // 6 waves: 3 gates x 2 j-halves

  __shared__ _Float16 wlds[3][32][LDW];
  __shared__ _Float16 hlds[16][LDW];
  __shared__ float    ghlds[3][32][17];

  // --- load resident W_hh slice ---
  const _Float16* wsrc = whh + (size_t)d*G3_*HH;
  #pragma unroll
  for (int it = 0; it < 16; ++it) {
    int idx = it*384 + tid;
    int row = idx >> 6;
    int c8 = (idx & 63) * 8;
    int gt = row >> 5, jj = row & 31;
    u4 v = *(const u4*)(wsrc + (size_t)(gt*HH + j0 + jj)*HH + c8);
    *(u4*)&wlds[gt][jj][c8] = v;
  }

  const int ejp = tid & 15;              // j-pair within slice
  const int eb  = tid >> 4;              // 0..15 batch within chunk (ew threads)
  const bool ew = (tid < 256);
  const int ejA = j0 + 2*ejp;

  unsigned long long* Tb = tagh + (size_t)d*2*BB*256;   // this direction's 2 parities

  float hj[2];
  float bhr[2], bhz[2], bhn[2];

  if (ew) {
    #pragma unroll
    for (int u = 0; u < 2; ++u) {
      bhr[u] = bhh[(size_t)d*G3_ + 0*HH + ejA + u];
      bhz[u] = bhh[(size_t)d*G3_ + 1*HH + ejA + u];
      bhn[u] = bhh[(size_t)d*G3_ + 2*HH + ejA + u];
      hj[u]  = h0[((size_t)(2*layer + d)*BB + b0 + eb)*HH + ejA + u];
    }
    h2 p; p[0] = (_Float16)hj[0]; p[1] = (_Float16)hj[1];
    unsigned long long ent = (unsigned long long)__builtin_bit_cast(unsigned, p) | (1ull << 32);
    unsigned long long* ptr = Tb + (size_t)0*BB*256 + (size_t)(b0 + eb)*256 + (member*16 + ejp);
    __hip_atomic_store(ptr, ent, __ATOMIC_RELAXED, __HIP_MEMORY_SCOPE_AGENT);
  }
  __syncthreads();   // wlds ready

  for (int s = 0; s < TL; ++s) {
    const int t = d ? (TL-1 - s) : s;
    const int rpar = s & 1, wpar = rpar ^ 1;
    const unsigned tgt = (unsigned)(s + 1);
    const unsigned long long* Trd = Tb + (size_t)rpar*BB*256;
    unsigned giR = 0, giZ = 0, giN = 0;
    unsigned long long E[16];
    if (ew) {
      // issue ALL 16 mailbox entry loads FIRST (LLC; verify drains only these)
      #pragma unroll
      for (int q = 0; q < 4; ++q)
        #pragma unroll
        for (int k = 0; k < 4; ++k) {
          int i = tid*2 + (k >> 1);            // pair-task index 0..511
          E[q*4+k] = __hip_atomic_load(
              Trd + (size_t)(b0 + (i >> 5))*256 + q*64 + (i & 31)*2 + (k & 1),
              __ATOMIC_RELAXED, __HIP_MEMORY_SCOPE_AGENT);
        }
    }
    __builtin_amdgcn_sched_barrier(0);       // pin: gi HBM loads issue AFTER E
    if (ew) {
      // gi for this step (HBM; younger than E -> not drained by verify)
      const _Float16* p = gi + ((size_t)d*BT_ + (size_t)(b0 + eb)*TL + t)*(size_t)G3_ + ejA;
      giR = *(const unsigned*)(p);
      giZ = *(const unsigned*)(p + HH);
      giN = *(const unsigned*)(p + 2*HH);
    }
    f4 acc = {0.f, 0.f, 0.f, 0.f};
    #pragma unroll
    for (int q = 0; q < 4; ++q) {
      if (ew) {
        // per-LANE verify + 32B thread-local retry (no barriers, no ballots)
        for (;;) {
          unsigned ok = 1u;
          #pragma unroll
          for (int k = 0; k < 4; ++k)
            ok &= (unsigned)((E[q*4+k] >> 32) >= tgt);
          if (ok) break;
          #pragma unroll
          for (int k = 0; k < 4; ++k) {
            int i = tid*2 + (k >> 1);
            E[q*4+k] = __hip_atomic_load(
                Trd + (size_t)(b0 + (i >> 5))*256 + q*64 + (i & 31)*2 + (k & 1),
                __ATOMIC_RELAXED, __HIP_MEMORY_SCOPE_AGENT);
          }
        }
        // stage quad q into hlds
        #pragma unroll
        for (int k = 0; k < 2; ++k) {
          int i = tid*2 + k;
          int b = i >> 5, p = i & 31;
          u2v dv; dv[0] = (unsigned)E[q*4 + k*2]; dv[1] = (unsigned)E[q*4 + k*2 + 1];
          *(u2v*)&hlds[b][q*128 + p*4] = dv;
        }
      }
      asm volatile("s_waitcnt lgkmcnt(0)" ::: "memory");   // ds_writes committed
      __builtin_amdgcn_s_barrier();                         // raw: vmcnt NOT drained
      __builtin_amdgcn_sched_barrier(0);
      // MFMA this quad's K-chunks
      #pragma unroll
      for (int kk = q*4; kk < q*4 + 4; ++kk) {
        h8 af = *(const h8*)&hlds[lo][kk*32 + hi*8];
        h8 bf = *(const h8*)&wlds[gate][jh*16 + lo][kk*32 + hi*8];
        acc = __builtin_amdgcn_mfma_f32_16x16x32_f16(af, bf, acc, 0, 0, 0);
      }
    }
    #pragma unroll
    for (int v = 0; v < 4; ++v)
      ghlds[gate][jh*16 + lo][hi*4 + v] = acc[v];   // [gate][j][b]
    __syncthreads();   // ghlds RAW (full drain fine; also frees hlds for next step)
    // --- elementwise GRU update + tagged h publish (fire-and-forget atomic) ---
    if (ew) {
      h2 pR = __builtin_bit_cast(h2, giR);
      h2 pZ = __builtin_bit_cast(h2, giZ);
      h2 pN = __builtin_bit_cast(h2, giN);
      h2 hnew; float hv[2];
      #pragma unroll
      for (int u = 0; u < 2; ++u) {
        float ir = (float)pR[u], iz = (float)pZ[u], inn = (float)pN[u];
        float hr = ghlds[0][2*ejp+u][eb] + bhr[u];
        float hz = ghlds[1][2*ejp+u][eb] + bhz[u];
        float hn = ghlds[2][2*ejp+u][eb] + bhn[u];
        float rr = 1.f/(1.f + __expf(-(ir + hr)));
        float zz = 1.f/(1.f + __expf(-(iz + hz)));
        float xx = inn + rr*hn;
        float nn = 1.f - 2.f/(__expf(2.f*xx) + 1.f);   // tanh, overflow-safe
        float h  = (1.f - zz)*nn + zz*hj[u];
        hj[u] = h; hnew[u] = (_Float16)h; hv[u] = h;
      }
      unsigned hu = __builtin_bit_cast(unsigned, hnew);
      unsigned long long ent = (unsigned long long)hu | ((unsigned long long)(s + 2) << 32);
      unsigned long long* ptr = Tb + (size_t)wpar*BB*256 + (size_t)(b0 + eb)*256 + (member*16 + ejp);
      __hip_atomic_store(ptr, ent, __ATOMIC_RELAXED, __HIP_MEMORY_SCOPE_AGENT);
      if (out_mid) {
        *(unsigned*)(out_mid + ((size_t)(b0+eb)*TL + t)*(size_t)(2*HH) + d*HH + ejA) = hu;
      } else {
        u2v ov; ov[0] = __builtin_bit_cast(unsigned, hv[0]); ov[1] = __builtin_bit_cast(unsigned, hv[1]);
        *(u2v*)(out_fin + ((size_t)(b0+eb)*TL + t)*(size_t)(2*HH) + d*HH + ejA) = ov;
      }
    }
    // no end barrier: next step's quad-0 barrier provides separation
  }
  if (ew) {
    #pragma unroll
    for (int u = 0; u < 2; ++u)
      hn_out[((size_t)(2*layer + d)*BB + b0 + eb)*HH + ejA + u] = hj[u];
  }
}

// ---------------- host launcher ----------------
extern "C" void kernel_launch(void* const* d_in, const int* in_sizes, int n_in,
                              void* d_out, int out_size, void* d_ws, size_t ws_size,
                              hipStream_t stream) {
  (void)in_sizes; (void)n_in; (void)out_size;
  const float* x   = (const float*)d_in[0];
  const float* h0  = (const float*)d_in[1];
  const float* wih = (const float*)d_in[2];
  const float* whh = (const float*)d_in[3];
  const float* bih = (const float*)d_in[4];
  const float* bhh = (const float*)d_in[5];
  float* out = (float*)d_out;

  char* ws = (char*)d_ws;
  size_t off = 0;
  auto alloc = [&](size_t bytes) {
    char* p = ws + off;
    off += (bytes + 255) & ~(size_t)255;
    return p;
  };
  _Float16* x16   = (_Float16*)alloc((size_t)BT_*II*2);          // 128 MB
  _Float16* mid16 = (_Float16*)alloc((size_t)BT_*II*2);          // 128 MB
  _Float16* gi16  = (_Float16*)alloc((size_t)2*BT_*G3_*2);       // 384 MB
  _Float16* wih16 = (_Float16*)alloc((size_t)NL*N2_*II*2);       // 12 MB
  _Float16* whh16 = (_Float16*)alloc((size_t)NL*N2_*HH*2);       // 6 MB
  unsigned long long* tagh = (unsigned long long*)alloc((size_t)NL*2*2*BB*256*8); // 1 MB
  if (off > ws_size) {
    fprintf(stderr, "kernel_launch: workspace too small: need %zu have %zu\n", off, ws_size);
    return;
  }

  hipMemsetAsync(tagh, 0, (size_t)NL*2*2*BB*256*8, stream);      // clear stale tags (per replay)
  cvt_f2h<<<2048, 256, 0, stream>>>(x,   x16,   (size_t)BT_*II/4);
  cvt_f2h<<<512,  256, 0, stream>>>(wih, wih16, (size_t)NL*N2_*II/4);
  cvt_f2h<<<512,  256, 0, stream>>>(whh, whh16, (size_t)NL*N2_*HH/4);

  float* hn = out + (size_t)BT_*II;   // h_n region: (4,64,512) after (B,T,2H)

  // layer 0
  gemm_gi<<<dim3(24, 512), 256, 0, stream>>>(x16, wih16, bih, gi16);
  gru_layer<<<128, 384, 0, stream>>>(gi16, whh16, bhh, h0, tagh,
                                     mid16, nullptr, hn, 0);
  // layer 1
  gemm_gi<<<dim3(24, 512), 256, 0, stream>>>(mid16, wih16 + (size_t)N2_*II, bih + N2_, gi16);
  gru_layer<<<128, 384, 0, stream>>>(gi16, whh16 + (size_t)N2_*HH, bhh + N2_, h0,
                                     tagh + (size_t)2*2*BB*256, nullptr, out, hn, 1);
}

// Round 16
// 7195.173 us; speedup vs baseline: 1.3533x; 1.1381x over previous
//
#include <hip/hip_runtime.h>
#include <stdint.h>
#include <stdio.h>

// Problem constants
#define TL 1024          // T
#define BB 64            // B
#define HH 512           // H
#define II 1024          // input size (== 2H for layer 2)
#define NL 2             // layers
#define BT_ (BB*TL)      // 65536
#define G3_ 1536         // 3H
#define N2_ 3072         // 2*3H (both dirs stacked)

typedef _Float16 h8 __attribute__((ext_vector_type(8)));
typedef _Float16 h4 __attribute__((ext_vector_type(4)));
typedef _Float16 h2 __attribute__((ext_vector_type(2)));
typedef float    f4 __attribute__((ext_vector_type(4)));
typedef unsigned int u4 __attribute__((ext_vector_type(4)));
typedef unsigned int u2v __attribute__((ext_vector_type(2)));

// ---------------- fp32 -> fp16 convert ----------------
__global__ void cvt_f2h(const float* __restrict__ src, _Float16* __restrict__ dst, size_t n4) {
  size_t i = (size_t)blockIdx.x*blockDim.x + threadIdx.x;
  size_t stride = (size_t)gridDim.x*blockDim.x;
  for (; i < n4; i += stride) {
    f4 v = ((const f4*)src)[i];
    h4 o;
    o[0] = (_Float16)v[0]; o[1] = (_Float16)v[1];
    o[2] = (_Float16)v[2]; o[3] = (_Float16)v[3];
    ((h4*)dst)[i] = o;
  }
}

// ---------------- gi GEMM (unchanged, proven) ----------------
#define LDA 40
__launch_bounds__(256)
__global__ void gemm_gi(const _Float16* __restrict__ A, const _Float16* __restrict__ Bw,
                        const float* __restrict__ bias, _Float16* __restrict__ gi)
{
  const int bn = blockIdx.x, bm = blockIdx.y;
  const int tid = threadIdx.x;
  const int wave = tid >> 6, lane = tid & 63;
  const int wm = wave >> 1, wn = wave & 1;
  const int lo = lane & 15, hi = lane >> 4;
  __shared__ _Float16 As[128*LDA];
  __shared__ _Float16 Bs[128*LDA];
  f4 acc[4][4] = {};
  const int r0 = tid >> 2, c0 = (tid & 3)*8;
  const _Float16* Ag = A + (size_t)(bm*128)*II;
  const _Float16* Bg = Bw + (size_t)(bn*128)*II;
  u4 a0 = *(const u4*)(Ag + (size_t)r0*II + c0);
  u4 a1 = *(const u4*)(Ag + (size_t)(64+r0)*II + c0);
  u4 b0 = *(const u4*)(Bg + (size_t)r0*II + c0);
  u4 b1 = *(const u4*)(Bg + (size_t)(64+r0)*II + c0);
  for (int kt = 0; kt < 32; ++kt) {
    __syncthreads();
    *(u4*)&As[r0*LDA + c0] = a0;
    *(u4*)&As[(64+r0)*LDA + c0] = a1;
    *(u4*)&Bs[r0*LDA + c0] = b0;
    *(u4*)&Bs[(64+r0)*LDA + c0] = b1;
    if (kt+1 < 32) {
      const int off = (kt+1)*32 + c0;
      a0 = *(const u4*)(Ag + (size_t)r0*II + off);
      a1 = *(const u4*)(Ag + (size_t)(64+r0)*II + off);
      b0 = *(const u4*)(Bg + (size_t)r0*II + off);
      b1 = *(const u4*)(Bg + (size_t)(64+r0)*II + off);
    }
    __syncthreads();
    h8 af[4], bf[4];
    #pragma unroll
    for (int i = 0; i < 4; ++i)
      af[i] = *(const h8*)&As[(wm*64 + i*16 + lo)*LDA + hi*8];
    #pragma unroll
    for (int j = 0; j < 4; ++j)
      bf[j] = *(const h8*)&Bs[(wn*64 + j*16 + lo)*LDA + hi*8];
    #pragma unroll
    for (int i = 0; i < 4; ++i)
      #pragma unroll
      for (int j = 0; j < 4; ++j)
        acc[i][j] = __builtin_amdgcn_mfma_f32_16x16x32_f16(af[i], bf[j], acc[i][j], 0, 0, 0);
  }
  const int nbase = bn*128 + wn*64;
  const int mbase = bm*128 + wm*64;
  #pragma unroll
  for (int j = 0; j < 4; ++j) {
    int n = nbase + j*16 + lo;
    int dir = (n >= G3_) ? 1 : 0;
    int row = n - dir*G3_;
    float bs = bias[n];
    #pragma unroll
    for (int i = 0; i < 4; ++i) {
      int m0 = mbase + i*16 + hi*4;
      #pragma unroll
      for (int v = 0; v < 4; ++v)
        gi[((size_t)dir*BT_ + (size_t)(m0+v))*G3_ + row] = (_Float16)(acc[i][j][v] + bs);
    }
  }
}

// ---------------- persistent GRU layer kernel (tagged-mailbox, quad-pipelined read) ----------------
// R8 EXACT REVERT - best measured configuration (3.04-3.10 ms/dispatch).
// 128 blocks. gg=bid&7: d=gg&1, g=gg>>1 (batch-chunk of 16). member=bid>>3 owns
// j-slice [member*32,+32), all 3 gates resident in LDS (96 rows W_hh).
// h exchange: 8B entries {h2 pair | tag<<32}, relaxed agent-scope 8B atomics
// (single-copy atomic; proven R6/R7). read step s: parity s&1, tag>=s+1; write
// end s: parity (s+1)&1, tag s+2, fire-and-forget. 2-step back-pressure: a
// writer's version-(s+2) publish is program-ordered after ALL its step-(s+1)
// reads, which gate on every member's version-(s+1) publish, which follows
// their complete step-s reads -> slot stable while readable (R6 induction).
// All 16 entry loads issued up-front (parallel LLC RTs); members consumed in
// 4 quads: per-LANE tag verify with 32B thread-local retry (no block-wide
// re-reads/ballots), stage quad to LDS, raw s_barrier + lgkmcnt(0) only (no
// vmcnt drain: later quads' loads stay in flight), MFMA the quad's 4 K-chunks.
// Barrier implies all lanes verified.
// NOTE (R9-R15 ledger): sentinel spin, monolithic verify, role-split waves,
// clean-queue loaders, flag-gated read, L2-tier dual-publish, and E-before-gi
// reorder ALL regressed (3.3-4.4 us/step vs this structure's 3.04). The floor
// is the serial agent-scope publish->detect chain; this schedule is the
// measured local optimum.
#define LDW 520
__launch_bounds__(384, 1)
__global__ void gru_layer(const _Float16* __restrict__ gi,     // [dir][b*T+t][1536]
                          const _Float16* __restrict__ whh,    // layer: [dir][1536][512]
                          const float* __restrict__ bhh,       // layer: [dir][1536]
                          const float* __restrict__ h0,        // [4][64][512]
                          unsigned long long* __restrict__ tagh, // layer: [d][par][64][256] u64
                          _Float16* __restrict__ out_mid,      // layer0: [b][t][1024] fp16
                          float* __restrict__ out_fin,         // layer1: [b][t][1024] fp32
                          float* __restrict__ hn_out,          // [4][64][512] fp32
                          int layer)
{
  const int bid = blockIdx.x;
  const int gg = bid & 7, d = gg & 1, g = gg >> 1;
  const int member = bid >> 3;
  const int j0 = member * 32, b0 = g * 16;
  const int tid = threadIdx.x;
  const int wave = tid >> 6, lane = tid & 63, lo = lane & 15, hi = lane >> 4;
  const int gate = wave >> 1, jh = wave & 1;     // 6 waves: 3 gates x 2 j-halves

  __shared__ _Float16 wlds[3][32][LDW];
  __shared__ _Float16 hlds[16][LDW];
  __shared__ float    ghlds[3][32][17];

  // --- load resident W_hh slice ---
  const _Float16* wsrc = whh + (size_t)d*G3_*HH;
  #pragma unroll
  for (int it = 0; it < 16; ++it) {
    int idx = it*384 + tid;
    int row = idx >> 6;
    int c8 = (idx & 63) * 8;
    int gt = row >> 5, jj = row & 31;
    u4 v = *(const u4*)(wsrc + (size_t)(gt*HH + j0 + jj)*HH + c8);
    *(u4*)&wlds[gt][jj][c8] = v;
  }

  const int ejp = tid & 15;              // j-pair within slice
  const int eb  = tid >> 4;              // 0..15 batch within chunk (ew threads)
  const bool ew = (tid < 256);
  const int ejA = j0 + 2*ejp;

  unsigned long long* Tb = tagh + (size_t)d*2*BB*256;   // this direction's 2 parities

  float hj[2];
  float bhr[2], bhz[2], bhn[2];

  if (ew) {
    #pragma unroll
    for (int u = 0; u < 2; ++u) {
      bhr[u] = bhh[(size_t)d*G3_ + 0*HH + ejA + u];
      bhz[u] = bhh[(size_t)d*G3_ + 1*HH + ejA + u];
      bhn[u] = bhh[(size_t)d*G3_ + 2*HH + ejA + u];
      hj[u]  = h0[((size_t)(2*layer + d)*BB + b0 + eb)*HH + ejA + u];
    }
    h2 p; p[0] = (_Float16)hj[0]; p[1] = (_Float16)hj[1];
    unsigned long long ent = (unsigned long long)__builtin_bit_cast(unsigned, p) | (1ull << 32);
    unsigned long long* ptr = Tb + (size_t)0*BB*256 + (size_t)(b0 + eb)*256 + (member*16 + ejp);
    __hip_atomic_store(ptr, ent, __ATOMIC_RELAXED, __HIP_MEMORY_SCOPE_AGENT);
  }
  __syncthreads();   // wlds ready

  for (int s = 0; s < TL; ++s) {
    const int t = d ? (TL-1 - s) : s;
    const int rpar = s & 1, wpar = rpar ^ 1;
    const unsigned tgt = (unsigned)(s + 1);
    const unsigned long long* Trd = Tb + (size_t)rpar*BB*256;
    unsigned giR = 0, giZ = 0, giN = 0;
    unsigned long long E[16];
    if (ew) {
      // gi for this step (HBM; retires first, hidden under mailbox RTs)
      const _Float16* p = gi + ((size_t)d*BT_ + (size_t)(b0 + eb)*TL + t)*(size_t)G3_ + ejA;
      giR = *(const unsigned*)(p);
      giZ = *(const unsigned*)(p + HH);
      giN = *(const unsigned*)(p + 2*HH);
      // issue ALL 16 mailbox entry loads up-front (4 quads x 4)
      #pragma unroll
      for (int q = 0; q < 4; ++q)
        #pragma unroll
        for (int k = 0; k < 4; ++k) {
          int i = tid*2 + (k >> 1);            // pair-task index 0..511
          E[q*4+k] = __hip_atomic_load(
              Trd + (size_t)(b0 + (i >> 5))*256 + q*64 + (i & 31)*2 + (k & 1),
              __ATOMIC_RELAXED, __HIP_MEMORY_SCOPE_AGENT);
        }
    }
    f4 acc = {0.f, 0.f, 0.f, 0.f};
    #pragma unroll
    for (int q = 0; q < 4; ++q) {
      if (ew) {
        // per-LANE verify + 32B thread-local retry (no barriers, no ballots)
        for (;;) {
          unsigned ok = 1u;
          #pragma unroll
          for (int k = 0; k < 4; ++k)
            ok &= (unsigned)((E[q*4+k] >> 32) >= tgt);
          if (ok) break;
          #pragma unroll
          for (int k = 0; k < 4; ++k) {
            int i = tid*2 + (k >> 1);
            E[q*4+k] = __hip_atomic_load(
                Trd + (size_t)(b0 + (i >> 5))*256 + q*64 + (i & 31)*2 + (k & 1),
                __ATOMIC_RELAXED, __HIP_MEMORY_SCOPE_AGENT);
          }
        }
        // stage quad q into hlds
        #pragma unroll
        for (int k = 0; k < 2; ++k) {
          int i = tid*2 + k;
          int b = i >> 5, p = i & 31;
          u2v dv; dv[0] = (unsigned)E[q*4 + k*2]; dv[1] = (unsigned)E[q*4 + k*2 + 1];
          *(u2v*)&hlds[b][q*128 + p*4] = dv;
        }
      }
      asm volatile("s_waitcnt lgkmcnt(0)" ::: "memory");   // ds_writes committed
      __builtin_amdgcn_s_barrier();                         // raw: vmcnt NOT drained
      __builtin_amdgcn_sched_barrier(0);
      // MFMA this quad's K-chunks
      #pragma unroll
      for (int kk = q*4; kk < q*4 + 4; ++kk) {
        h8 af = *(const h8*)&hlds[lo][kk*32 + hi*8];
        h8 bf = *(const h8*)&wlds[gate][jh*16 + lo][kk*32 + hi*8];
        acc = __builtin_amdgcn_mfma_f32_16x16x32_f16(af, bf, acc, 0, 0, 0);
      }
    }
    #pragma unroll
    for (int v = 0; v < 4; ++v)
      ghlds[gate][jh*16 + lo][hi*4 + v] = acc[v];   // [gate][j][b]
    __syncthreads();   // ghlds RAW (full drain fine; also frees hlds for next step)
    // --- elementwise GRU update + tagged h publish (fire-and-forget atomic) ---
    if (ew) {
      h2 pR = __builtin_bit_cast(h2, giR);
      h2 pZ = __builtin_bit_cast(h2, giZ);
      h2 pN = __builtin_bit_cast(h2, giN);
      h2 hnew; float hv[2];
      #pragma unroll
      for (int u = 0; u < 2; ++u) {
        float ir = (float)pR[u], iz = (float)pZ[u], inn = (float)pN[u];
        float hr = ghlds[0][2*ejp+u][eb] + bhr[u];
        float hz = ghlds[1][2*ejp+u][eb] + bhz[u];
        float hn = ghlds[2][2*ejp+u][eb] + bhn[u];
        float rr = 1.f/(1.f + __expf(-(ir + hr)));
        float zz = 1.f/(1.f + __expf(-(iz + hz)));
        float xx = inn + rr*hn;
        float nn = 1.f - 2.f/(__expf(2.f*xx) + 1.f);   // tanh, overflow-safe
        float h  = (1.f - zz)*nn + zz*hj[u];
        hj[u] = h; hnew[u] = (_Float16)h; hv[u] = h;
      }
      unsigned hu = __builtin_bit_cast(unsigned, hnew);
      unsigned long long ent = (unsigned long long)hu | ((unsigned long long)(s + 2) << 32);
      unsigned long long* ptr = Tb + (size_t)wpar*BB*256 + (size_t)(b0 + eb)*256 + (member*16 + ejp);
      __hip_atomic_store(ptr, ent, __ATOMIC_RELAXED, __HIP_MEMORY_SCOPE_AGENT);
      if (out_mid) {
        *(unsigned*)(out_mid + ((size_t)(b0+eb)*TL + t)*(size_t)(2*HH) + d*HH + ejA) = hu;
      } else {
        u2v ov; ov[0] = __builtin_bit_cast(unsigned, hv[0]); ov[1] = __builtin_bit_cast(unsigned, hv[1]);
        *(u2v*)(out_fin + ((size_t)(b0+eb)*TL + t)*(size_t)(2*HH) + d*HH + ejA) = ov;
      }
    }
    // no end barrier: next step's quad-0 barrier provides separation
  }
  if (ew) {
    #pragma unroll
    for (int u = 0; u < 2; ++u)
      hn_out[((size_t)(2*layer + d)*BB + b0 + eb)*HH + ejA + u] = hj[u];
  }
}

// ---------------- host launcher ----------------
extern "C" void kernel_launch(void* const* d_in, const int* in_sizes, int n_in,
                              void* d_out, int out_size, void* d_ws, size_t ws_size,
                              hipStream_t stream) {
  (void)in_sizes; (void)n_in; (void)out_size;
  const float* x   = (const float*)d_in[0];
  const float* h0  = (const float*)d_in[1];
  const float* wih = (const float*)d_in[2];
  const float* whh = (const float*)d_in[3];
  const float* bih = (const float*)d_in[4];
  const float* bhh = (const float*)d_in[5];
  float* out = (float*)d_out;

  char* ws = (char*)d_ws;
  size_t off = 0;
  auto alloc = [&](size_t bytes) {
    char* p = ws + off;
    off += (bytes + 255) & ~(size_t)255;
    return p;
  };
  _Float16* x16   = (_Float16*)alloc((size_t)BT_*II*2);          // 128 MB
  _Float16* mid16 = (_Float16*)alloc((size_t)BT_*II*2);          // 128 MB
  _Float16* gi16  = (_Float16*)alloc((size_t)2*BT_*G3_*2);       // 384 MB
  _Float16* wih16 = (_Float16*)alloc((size_t)NL*N2_*II*2);       // 12 MB
  _Float16* whh16 = (_Float16*)alloc((size_t)NL*N2_*HH*2);       // 6 MB
  unsigned long long* tagh = (unsigned long long*)alloc((size_t)NL*2*2*BB*256*8); // 1 MB
  if (off > ws_size) {
    fprintf(stderr, "kernel_launch: workspace too small: need %zu have %zu\n", off, ws_size);
    return;
  }

  hipMemsetAsync(tagh, 0, (size_t)NL*2*2*BB*256*8, stream);      // clear stale tags (per replay)
  cvt_f2h<<<2048, 256, 0, stream>>>(x,   x16,   (size_t)BT_*II/4);
  cvt_f2h<<<512,  256, 0, stream>>>(wih, wih16, (size_t)NL*N2_*II/4);
  cvt_f2h<<<512,  256, 0, stream>>>(whh, whh16, (size_t)NL*N2_*HH/4);

  float* hn = out + (size_t)BT_*II;   // h_n region: (4,64,512) after (B,T,2H)

  // layer 0
  gemm_gi<<<dim3(24, 512), 256, 0, stream>>>(x16, wih16, bih, gi16);
  gru_layer<<<128, 384, 0, stream>>>(gi16, whh16, bhh, h0, tagh,
                                     mid16, nullptr, hn, 0);
  // layer 1
  gemm_gi<<<dim3(24, 512), 256, 0, stream>>>(mid16, wih16 + (size_t)N2_*II, bih + N2_, gi16);
  gru_layer<<<128, 384, 0, stream>>>(gi16, whh16 + (size_t)N2_*HH, bhh + N2_, h0,
                                     tagh + (size_t)2*2*BB*256, nullptr, out, hn, 1);
}